// Round 7
// baseline (181.732 us; speedup 1.0000x reference)
//
#include <hip/hip_runtime.h>
#include <cstdint>
#include <cstddef>

#define B_ 256
#define IW_ 3072
#define L_ 8
#define NN_ 7
#define FCIN_ 16384
#define OUTW_ 10
#define ICST 40            // ushorts per (row,col) cell: 32 ic + 8 pad
#define YPLANE (324 * ICST)

typedef short short8 __attribute__((ext_vector_type(8)));
typedef float f32x4 __attribute__((ext_vector_type(4)));

__device__ __forceinline__ ushort f2bf(float x) {
    uint u = __float_as_uint(x);
    return (ushort)((u + 0x7fffu + ((u >> 16) & 1u)) >> 16);
}
__device__ __forceinline__ float bf2f(ushort b) { return __uint_as_float(((uint)b) << 16); }

// ---------- repack conv1 weights into MFMA frag-linear hi/lo bf16 ----------
// layout: [l8][mt4][lane64][j8]; oc = mt*16 + (lane&15); k = (lane>>4)*8 + j (k=ic*9+tap, 27..31 pad)
__global__ void k_repack_w1f(const float* __restrict__ w1, ushort* __restrict__ w1fh,
                             ushort* __restrict__ w1fl) {
    int i = blockIdx.x * 256 + threadIdx.x;
    if (i >= 16384) return;
    int j    = i & 7;
    int lane = (i >> 3) & 63;
    int mt   = (i >> 9) & 3;
    int l    = i >> 11;
    int fr = lane & 15, fq = lane >> 4;
    int oc = mt * 16 + fr;
    int k = fq * 8 + j;
    float w = (k < 27) ? w1[(size_t)(l * 64 + oc) * 27 + k] : 0.f;
    ushort hb = f2bf(w);
    w1fh[i] = hb;
    w1fl[i] = f2bf(w - bf2f(hb));
}

// ---------- repack conv2 weights into MFMA frag-linear hi/lo bf16 ----------
// layout: [l8][icc2][tap9][mt4][lane64][j8]; oc = mt*16 + (lane&15); ic = icc*32 + (lane>>4)*8 + j
__global__ void k_repack_w2(const float* __restrict__ w2, ushort* __restrict__ w2h,
                            ushort* __restrict__ w2l) {
    int i = blockIdx.x * 256 + threadIdx.x;
    if (i >= 294912) return;
    int j    = i & 7;
    int lane = (i >> 3) & 63;
    int mt   = (i >> 9) & 3;
    int tap  = (i >> 11) % 9;
    int icc  = (i / 18432) & 1;
    int l    = i / 36864;
    int fr = lane & 15, fq = lane >> 4;
    int oc = mt * 16 + fr;
    int ic = icc * 32 + fq * 8 + j;
    float w = w2[(((size_t)l * 64 + oc) * 64 + ic) * 9 + tap];
    ushort hb = f2bf(w);
    w2h[i] = hb;
    w2l[i] = f2bf(w - bf2f(hb));
}

// ---------- mixture ----------
__global__ __launch_bounds__(256) void k_mixture(const float* __restrict__ x, const float* __restrict__ nw,
                                                 const float* __restrict__ nb, float* __restrict__ mix) {
    __shared__ float red[4 * NN_];
    __shared__ float bes[NN_];
    int b = blockIdx.x, tid = threadIdx.x;
    const float* xb = x + (size_t)b * IW_;
    float p[NN_];
#pragma unroll
    for (int n = 0; n < NN_; ++n) p[n] = 0.f;
    for (int i = tid; i < IW_; i += 256) {
        float xv = xb[i];
#pragma unroll
        for (int n = 0; n < NN_; ++n) p[n] = fmaf(xv, nw[n * IW_ + i], p[n]);
    }
#pragma unroll
    for (int n = 0; n < NN_; ++n) {
        float v = p[n];
        for (int off = 32; off > 0; off >>= 1) v += __shfl_xor(v, off);
        if ((tid & 63) == 0) red[(tid >> 6) * NN_ + n] = v;
    }
    __syncthreads();
    if (tid < NN_) {
        float s = red[tid] + red[NN_ + tid] + red[2 * NN_ + tid] + red[3 * NN_ + tid] + nb[tid];
        bes[tid] = 1.f / (1.f + expf(-s));
    }
    __syncthreads();
    if (tid < L_) {
        int leaf = tid;
        float b0 = bes[0];
        float t0 = ((leaf >> 2) & 1) ? b0 : 1.f - b0;
        float b1v = bes[1 + ((leaf >> 2) & 1)];
        float t1 = ((leaf >> 1) & 1) ? b1v : 1.f - b1v;
        float b2v = bes[3 + ((leaf >> 1) & 3)];
        float t2 = (leaf & 1) ? b2v : 1.f - b2v;
        mix[b * L_ + leaf] = t0 * t1 * t2;
    }
}

// ---------- fully-MFMA fused kernel, software-pipelined via double-buffered y tiles ----------
// block = sample (grid 256 = 1/CU), 512 thr = 8 waves, 16 steps (8 leaves x 2 icc).
// Iter i: conv1(i+1) -> buf[(i+1)&1]  ||  conv2(i) <- buf[i&1]; ONE barrier/step.
// conv2 wave tile (2mt x 4nt): halves global A-frag traffic vs (4,2), moves load to LDS pipe.
__global__ __launch_bounds__(512, 2) void k_fused(const float* __restrict__ x,
                                                  const ushort* __restrict__ w1fh, const ushort* __restrict__ w1fl,
                                                  const float* __restrict__ cb1,
                                                  const ushort* __restrict__ w2h, const ushort* __restrict__ w2l,
                                                  const float* __restrict__ cb2, const float* __restrict__ mixw,
                                                  float* __restrict__ out1, int boff) {
    __shared__ __align__(16) ushort smem[4 * YPLANE];        // buf0{yh,yl} | buf1{yh,yl} = 103.7 KB
    float* xpad = (float*)(smem + 2 * YPLANE);               // prologue-only alias of buf1

    int tid = threadIdx.x;
    int bl = blockIdx.x;
    int b = boff + bl;
    int lane = tid & 63, wid = tid >> 6;
    int fr = lane & 15, fq = lane >> 4;
    int g = wid & 1, ng = wid >> 1;                          // conv2: mts {2g,2g+1}, nts {4ng..4ng+3}

    // ---- prologue: xpad zero + fill ----
    for (int i = tid; i < 3 * 34 * 34; i += 512) xpad[i] = 0.f;
    __syncthreads();
    for (int i = tid; i < 3072; i += 512) {
        int ch = i >> 10, rr = (i >> 5) & 31, cc = i & 31;
        xpad[(ch * 34 + rr + 1) * 34 + cc + 1] = x[(size_t)b * IW_ + i];
    }
    __syncthreads();

    // ---- build leaf-invariant conv1 B-frags (im2col) in registers ----
    short8 Bh[8], Bl[8];
#pragma unroll
    for (int i = 0; i < 8; ++i) {
        int nt = wid * 8 + i;
        int pos = nt * 16 + fr;          // pre-pool position, row-major 32x32
        int r = pos >> 5, c = pos & 31;
#pragma unroll
        for (int j = 0; j < 8; ++j) {
            int k = fq * 8 + j;          // k = ic*9 + tap
            float xv = 0.f;
            if (k < 27) {
                int ic = k / 9;
                int tap = k - ic * 9;
                int dr = tap / 3, dc = tap - dr * 3;
                xv = xpad[(ic * 34 + r + dr) * 34 + (c + dc)];
            }
            ushort hb = f2bf(xv);
            Bh[i][j] = (short)hb;
            Bl[i][j] = (short)f2bf(xv - bf2f(hb));
        }
    }
    __syncthreads();
    {   // zero all 4 y planes (borders stay zero forever)
        uint4 z; z.x = z.y = z.z = z.w = 0u;
        for (int i = tid; i < (4 * YPLANE) / 8; i += 512) ((uint4*)smem)[i] = z;
    }
    __syncthreads();

    f32x4 acc[2][4], oacc[2][4];
#pragma unroll
    for (int m = 0; m < 2; ++m)
#pragma unroll
        for (int nl = 0; nl < 4; ++nl) { acc[m][nl] = (f32x4)0.f; oacc[m][nl] = (f32x4)0.f; }

    auto CONV1 = [&](int s) {
        int l = s >> 1, icc = s & 1;
        ushort* ybh = smem + (size_t)(s & 1) * 2 * YPLANE;
        ushort* ybl = ybh + YPLANE;
#pragma unroll
        for (int mt2 = 0; mt2 < 2; ++mt2) {
            int mtg = icc * 2 + mt2;
            short8 ah = *(const short8*)(w1fh + ((size_t)(l * 4 + mtg) * 64 + lane) * 8);
            short8 al = *(const short8*)(w1fl + ((size_t)(l * 4 + mtg) * 64 + lane) * 8);
            f32x4 a1[8];
#pragma unroll
            for (int i = 0; i < 8; ++i) {
                f32x4 t = (f32x4)0.f;
                t = __builtin_amdgcn_mfma_f32_16x16x32_bf16(ah, Bh[i], t, 0, 0, 0);
                t = __builtin_amdgcn_mfma_f32_16x16x32_bf16(ah, Bl[i], t, 0, 0, 0);
                t = __builtin_amdgcn_mfma_f32_16x16x32_bf16(al, Bh[i], t, 0, 0, 0);
                a1[i] = t;
            }
            float4 bias4 = *(const float4*)(cb1 + l * 64 + mtg * 16 + fq * 4);
            float bb[4] = {bias4.x, bias4.y, bias4.z, bias4.w};
#pragma unroll
            for (int g4 = 0; g4 < 4; ++g4) {
                int i = (g4 & 1) + (g4 >> 1) * 4;   // {0,1,4,5}; pool partner i+2
                ushort hb[4], lb[4];
#pragma unroll
                for (int j2 = 0; j2 < 4; ++j2) {
                    float m0 = fmaxf(a1[i][j2], a1[i + 2][j2]);
                    float m1 = fmaxf(m0, __shfl_xor(m0, 1));
                    float v = fmaxf(m1 + bb[j2], 0.f);
                    ushort h = f2bf(v);
                    hb[j2] = h;
                    lb[j2] = f2bf(v - bf2f(h));
                }
                if ((fr & 1) == 0) {
                    int pr = 2 * wid + (i >> 2);
                    int pc = ((i & 1) * 16 + fr) >> 1;
                    int off = ((pr + 1) * 18 + (pc + 1)) * ICST + mt2 * 16 + fq * 4;
                    uint2 H, Lw;
                    H.x = (uint)hb[0] | ((uint)hb[1] << 16); H.y = (uint)hb[2] | ((uint)hb[3] << 16);
                    Lw.x = (uint)lb[0] | ((uint)lb[1] << 16); Lw.y = (uint)lb[2] | ((uint)lb[3] << 16);
                    *(uint2*)&ybh[off] = H;
                    *(uint2*)&ybl[off] = Lw;
                }
            }
        }
    };

    auto CONV2 = [&](int s) {
        int l = s >> 1, icc = s & 1;
        const ushort* ybh = smem + (size_t)(s & 1) * 2 * YPLANE;
        const ushort* ybl = ybh + YPLANE;
        const ushort* wa_h = w2h + (size_t)((l * 2 + icc) * 9) * 4 * 512;
        const ushort* wa_l = w2l + (size_t)((l * 2 + icc) * 9) * 4 * 512;
#pragma unroll
        for (int kh = 0; kh < 3; ++kh)
#pragma unroll
            for (int kw = 0; kw < 3; ++kw) {
                int tap = kh * 3 + kw;
                short8 ah[2], al[2];
#pragma unroll
                for (int m = 0; m < 2; ++m) {
                    int mt = 2 * g + m;
                    ah[m] = *(const short8*)(wa_h + ((size_t)(tap * 4 + mt) * 64 + lane) * 8);
                    al[m] = *(const short8*)(wa_l + ((size_t)(tap * 4 + mt) * 64 + lane) * 8);
                }
#pragma unroll
                for (int nl = 0; nl < 4; ++nl) {
                    int nt = 4 * ng + nl;
                    int off = ((nt + kh) * 18 + (fr + kw)) * ICST + fq * 8;
                    short8 bh = *(const short8*)(ybh + off);
                    short8 bv = *(const short8*)(ybl + off);
#pragma unroll
                    for (int m = 0; m < 2; ++m) {
                        acc[m][nl] = __builtin_amdgcn_mfma_f32_16x16x32_bf16(ah[m], bh, acc[m][nl], 0, 0, 0);
                        acc[m][nl] = __builtin_amdgcn_mfma_f32_16x16x32_bf16(ah[m], bv, acc[m][nl], 0, 0, 0);
                        acc[m][nl] = __builtin_amdgcn_mfma_f32_16x16x32_bf16(al[m], bh, acc[m][nl], 0, 0, 0);
                    }
                }
            }
        if (icc) {  // leaf epilogue: bias + relu + mixture accumulate
            float mx = mixw[(size_t)b * 8 + l];
#pragma unroll
            for (int m = 0; m < 2; ++m)
#pragma unroll
                for (int j = 0; j < 4; ++j) {
                    float bias = cb2[l * 64 + (2 * g + m) * 16 + fq * 4 + j];
#pragma unroll
                    for (int nl = 0; nl < 4; ++nl) {
                        float v = fmaxf(acc[m][nl][j] + bias, 0.f);
                        oacc[m][nl][j] = fmaf(mx, v, oacc[m][nl][j]);
                        acc[m][nl][j] = 0.f;
                    }
                }
        }
    };

    CONV1(0);
    __syncthreads();
#pragma unroll 2
    for (int i = 0; i < 16; ++i) {
        if (i < 15) CONV1(i + 1);
        CONV2(i);
        __syncthreads();
    }

    // ---- store out1 [bl][64 oc][256 pos] fp32 ----
#pragma unroll
    for (int m = 0; m < 2; ++m)
#pragma unroll
        for (int nl = 0; nl < 4; ++nl)
#pragma unroll
            for (int j = 0; j < 4; ++j) {
                int oc = (2 * g + m) * 16 + fq * 4 + j;
                int pos = (4 * ng + nl) * 16 + fr;
                out1[((size_t)bl * 64 + oc) * 256 + pos] = oacc[m][nl][j];
            }
}

// ---------- fc: [bc][16384] @ [10][16384]^T + b ----------
__global__ __launch_bounds__(256) void k_fc(const float* __restrict__ out1, const float* __restrict__ fcw,
                                            const float* __restrict__ fcb, float* __restrict__ out, int boff) {
    __shared__ float red[4][OUTW_];
    int tid = threadIdx.x;
    int bl = blockIdx.x;
    const float4* flat = (const float4*)(out1 + (size_t)bl * FCIN_);
    float pj[OUTW_];
#pragma unroll
    for (int j = 0; j < OUTW_; ++j) pj[j] = 0.f;
    for (int i = tid; i < FCIN_ / 4; i += 256) {
        float4 v = flat[i];
#pragma unroll
        for (int j = 0; j < OUTW_; ++j) {
            float4 w = ((const float4*)(fcw + (size_t)j * FCIN_))[i];
            pj[j] += v.x * w.x + v.y * w.y + v.z * w.z + v.w * w.w;
        }
    }
#pragma unroll
    for (int j = 0; j < OUTW_; ++j) {
        float v = pj[j];
        for (int off = 32; off > 0; off >>= 1) v += __shfl_xor(v, off);
        if ((tid & 63) == 0) red[tid >> 6][j] = v;
    }
    __syncthreads();
    if (tid < OUTW_) {
        float s = red[0][tid] + red[1][tid] + red[2][tid] + red[3][tid] + fcb[tid];
        out[(size_t)(boff + bl) * OUTW_ + tid] = s;
    }
}

extern "C" void kernel_launch(void* const* d_in, const int* in_sizes, int n_in,
                              void* d_out, int out_size, void* d_ws, size_t ws_size,
                              hipStream_t stream) {
    const float* x   = (const float*)d_in[0];
    const float* nw  = (const float*)d_in[1];
    const float* nb  = (const float*)d_in[2];
    const float* w1  = (const float*)d_in[3];
    const float* cb1 = (const float*)d_in[4];
    const float* w2  = (const float*)d_in[5];
    const float* cb2 = (const float*)d_in[6];
    const float* fcw = (const float*)d_in[7];
    const float* fcb = (const float*)d_in[8];
    float* out = (float*)d_out;

    float*  ws   = (float*)d_ws;
    float*  mix  = ws;                        // 2048 f
    ushort* w1fh = (ushort*)(mix + 2048);     // 16384 us
    ushort* w1fl = w1fh + 16384;              // 16384 us
    ushort* w2h  = w1fl + 16384;              // 294912 us
    ushort* w2l  = w2h + 294912;              // 294912 us
    float*  out1 = (float*)(w2l + 294912);    // Bc * 16384 f

    // fixed bytes: 2048*4 + 2*16384*2 + 2*294912*2 = 1253376; out1 per sample = 65536 B
    long avail = (long)ws_size - 1253376L;
    int Bc = (int)(avail / 65536L);
    if (Bc > B_) Bc = B_;
    if (Bc < 1) Bc = 1;

    k_repack_w1f<<<16384 / 256, 256, 0, stream>>>(w1, w1fh, w1fl);
    k_repack_w2<<<294912 / 256, 256, 0, stream>>>(w2, w2h, w2l);
    k_mixture<<<B_, 256, 0, stream>>>(x, nw, nb, mix);

    for (int boff = 0; boff < B_; boff += Bc) {
        int bc = (B_ - boff < Bc) ? (B_ - boff) : Bc;
        k_fused<<<bc, 512, 0, stream>>>(x, w1fh, w1fl, cb1, w2h, w2l, cb2, mix, out1, boff);
        k_fc<<<bc, 256, 0, stream>>>(out1, fcw, fcb, out, boff);
    }
}